// Round 13
// baseline (122.106 us; speedup 1.0000x reference)
//
#include <hip/hip_runtime.h>
#include <math.h>

// SSIM char-matcher: img (1,1,1024,768) f32, chars (95,1,16,6) f32 -> argmax idx [64][128] int32
// H=16, W=6, WIN=3, tiles T=8192 (64 rows x 128 cols), refs R=95 (pad to 96)
//
// R13 "RegGEMM": lane = tile. Block = 64 tiles x 96 refs x 24 px (px-quarter);
// 512 thr = 8 waves, wave owns 12 refs (all 24 px, all 64 tiles).
// Per px: 9 taps + mu/sig read ONCE per lane (11 ds_read_b32), reused across
// the wave's 12 refs; ref rows are wave-uniform -> broadcast global loads
// (L2), never LDS. Main loop: zero barriers, zero staging, tiny LDS (24.6KB)
// -> 2 blocks/CU, 4 waves/SIMD. R7 was LDS(19us)+VALU(18us) co-bound at 50us;
// this removes the LDS stream.

static constexpr float kC1 = 1.0e-4f;   // 0.01^2
static constexpr float kC2 = 9.0e-4f;   // 0.03^2

struct KF { float k[9]; };

__device__ __forceinline__ int refl(int x, int n) {
  if (x < 0) return -x;
  if (x >= n) return 2 * n - 2 - x;
  return x;
}

// ---------------- Kernel 1: per-ref precompute ----------------
// refdata: [hw 96][r 96][12 floats] (row = 48 B, 16B-aligned).
// Row: f0..8 = 2*k[k]*Rp[k] (DOUBLED), f9 = 2*mu_r (DOUBLED),
// f10 = mu_r^2 + C1, f11 = sig_r + C2.  r=95 is padding (never argmax'd).
__global__ __launch_bounds__(128) void refprep_kernel(
    const float* __restrict__ chars, float* __restrict__ refdata,
    float* __restrict__ densR, KF kf) {
  const int hw = blockIdx.x;   // 0..95
  const int r = threadIdx.x;   // 0..127
  if (r >= 96) return;
  float* row = refdata + ((size_t)hw * 96 + r) * 12;
  const int h = hw / 6, w = hw % 6;
  if (r < 95) {
    const float* cb = chars + r * 96;
    float mu = 0.f, ex2 = 0.f;
    float wrv[9];
#pragma unroll
    for (int i = 0; i < 3; ++i) {
      const int hh = refl(h + i - 1, 16);
#pragma unroll
      for (int j = 0; j < 3; ++j) {
        const int ww = refl(w + j - 1, 6);
        const float p = cb[hh * 6 + ww];
        const float kv = kf.k[i * 3 + j];
        wrv[i * 3 + j] = 2.0f * kv * p;
        mu += kv * p;
        ex2 += kv * p * p;
      }
    }
    const float sig = ex2 - mu * mu;
#pragma unroll
    for (int k = 0; k < 9; ++k) row[k] = wrv[k];
    row[9]  = 2.0f * mu;
    row[10] = mu * mu + kC1;
    row[11] = sig + kC2;
  } else {
#pragma unroll
    for (int k = 0; k < 9; ++k) row[k] = 0.f;
    row[9]  = 0.f;
    row[10] = kC1;
    row[11] = kC2;
  }
  if (hw == 0) {
    if (r < 95) {
      float s = 0.f;
      for (int i = 0; i < 96; ++i) s += chars[r * 96 + i];
      densR[r] = s * (1.0f / 96.0f);
    } else {
      densR[r] = 0.f;
    }
  }
}

// ---------------- Kernel 2a: main SSIM (px-quarter, reg-resident taps) ----------------
// Grid 512 = (64 rows) x (2 tile-halves of 64) x (4 px-quarters of 24).
// part[q 4][b2 128][r 96][t 64]; densP[q 4][8192].
__global__ __launch_bounds__(512, 2)
void ssim_reg_kernel(
    const float* __restrict__ img, const float* __restrict__ refdata,
    float* __restrict__ part, float* __restrict__ densP, KF kf) {
  __shared__ float padT[3072];    // [6 prow][8 pcol][64 tile]
  __shared__ float statT[3072];   // [2][24 px][64 tile]

  const int tid = threadIdx.x;
  const int lane = tid & 63;      // tile 0..63
  const int w = tid >> 6;         // wave 0..7 -> refs [12w, 12w+12)
  const int blk = blockIdx.x;
  const int q = blk & 3;          // px-quarter: pixel rows [4q, 4q+4)
  const int b2 = blk >> 2;        // 0..127
  const int row0 = b2 >> 1;       // tile-row 0..63
  const int ch = b2 & 1;          // tile-half: tiles [64ch, 64ch+64)

  // Phase A: reflect-padded rows 4q-1..4q+4 of this tile-row, transposed.
  for (int idx = tid; idx < 3072; idx += 512) {
    const int c = idx >> 6, tl = idx & 63;
    const int pr = c >> 3, pc = c & 7;
    const int h = refl(q * 4 + pr - 1, 16), ww = refl(pc - 1, 6);
    padT[idx] = img[(row0 * 16 + h) * 768 + ch * 384 + tl * 6 + ww];
  }
  __syncthreads();

  // Quarter tile-density partial (4 interior rows x 6 cols), raw sum.
  if (tid < 64) {
    float s = 0.f;
    for (int pr = 1; pr <= 4; ++pr)
      for (int pc = 1; pc <= 6; ++pc)
        s += padT[(pr * 8 + pc) * 64 + tid];
    densP[q * 8192 + row0 * 128 + ch * 64 + tid] = s;
  }
  // Phase B: per-(local px, tile) stats: mu, sig.
  for (int idx = tid; idx < 1536; idx += 512) {
    const int hwl = idx >> 6, tl = idx & 63;
    const int hl = hwl / 6, wl = hwl - hl * 6;
    float mu = 0.f, ex2 = 0.f;
#pragma unroll
    for (int i = 0; i < 3; ++i)
#pragma unroll
      for (int j = 0; j < 3; ++j) {
        const float p = padT[((hl + i) * 8 + (wl + j)) * 64 + tl];
        const float kv = kf.k[i * 3 + j];
        mu += kv * p;
        ex2 += kv * p * p;
      }
    statT[idx] = mu;
    statT[1536 + idx] = ex2 - mu * mu;
  }
  __syncthreads();

  float score[12];
#pragma unroll
  for (int j = 0; j < 12; ++j) score[j] = 0.f;

  int tapoff = lane;              // float index of window origin (r6=0,c6=0)
  int statoff = lane;
  int c6 = 0;
  const float* refpx = refdata + (size_t)(q * 24) * 1152 + w * 12 * 12;

#pragma unroll 1
  for (int p = 0; p < 24; ++p) {
    // 9 taps + stats for this lane's tile at this px (all LDS b32, reused x12 refs)
    float t0 = padT[tapoff];
    float t1 = padT[tapoff + 64];
    float t2 = padT[tapoff + 128];
    float t3 = padT[tapoff + 512];
    float t4 = padT[tapoff + 576];
    float t5 = padT[tapoff + 640];
    float t6 = padT[tapoff + 1024];
    float t7 = padT[tapoff + 1088];
    float t8 = padT[tapoff + 1152];
    const float mu = statT[statoff];
    const float sg = statT[1536 + statoff];
    const float mt2 = mu * mu;

#pragma unroll
    for (int j = 0; j < 12; ++j) {
      // Wave-uniform ref row: broadcast global loads (one L2 line each).
      const float* rw = refpx + j * 12;
      const float4 wa = *(const float4*)(rw);
      const float4 wb = *(const float4*)(rw + 4);
      const float4 wc = *(const float4*)(rw + 8);
      float ev = fmaf(t0, wa.x, kC2);
      ev = fmaf(t1, wa.y, ev);
      ev = fmaf(t2, wa.z, ev);
      ev = fmaf(t3, wa.w, ev);
      ev = fmaf(t4, wb.x, ev);
      ev = fmaf(t5, wb.y, ev);
      ev = fmaf(t6, wb.z, ev);
      ev = fmaf(t7, wb.w, ev);
      ev = fmaf(t8, wc.x, ev);
      // wc.y = 2*mu_r, wc.z = mu_r^2+C1, wc.w = sig_r+C2
      const float am = mu * wc.y;              // 2*mt*mr
      const float n1 = am + kC1;
      const float n2 = ev - am;                // 2*sig_tr + C2
      const float d1 = mt2 + wc.z;             // mt^2+mr^2+C1
      const float d2 = sg + wc.w;
      const float r0v = __builtin_amdgcn_rcpf(d1 * d2);  // ~1-ulp (absmax 0 since R8)
      score[j] = fmaf(n1 * n2, r0v, score[j]);
    }

    tapoff += (c6 == 5) ? 192 : 64;   // col step; row wrap: +3 window cols
    c6 = (c6 == 5) ? 0 : c6 + 1;
    statoff += 64;
    refpx += 1152;
  }

  // Write per-(ref, tile) partials: coalesced 64-lane rows.
  float* dst = part + ((size_t)q * 128 + b2) * 6144 + (w * 12) * 64 + lane;
#pragma unroll
  for (int j = 0; j < 12; ++j) dst[j * 64] = score[j];
}

// ---------------- Kernel 2b: combine quarters + density + argmax ----------------
__global__ __launch_bounds__(512) void combine4_kernel(
    const float* __restrict__ part, const float* __restrict__ densP,
    const float* __restrict__ densR, int* __restrict__ out) {
  __shared__ float sb2[64 * 97];
  __shared__ float sdens[64];
  const int tid = threadIdx.x;
  const int b2 = blockIdx.x;          // 0..127

  for (int idx = tid; idx < 6144; idx += 512) {
    const int r = idx >> 6, t = idx & 63;
    const float s = part[(size_t)(0 * 128 + b2) * 6144 + idx]
                  + part[(size_t)(1 * 128 + b2) * 6144 + idx]
                  + part[(size_t)(2 * 128 + b2) * 6144 + idx]
                  + part[(size_t)(3 * 128 + b2) * 6144 + idx];
    sb2[t * 97 + r] = s;
  }
  if (tid < 64) {
    const int gt = (b2 >> 1) * 128 + (b2 & 1) * 64 + tid;
    sdens[tid] = (densP[gt] + densP[8192 + gt] + densP[16384 + gt]
                  + densP[24576 + gt]) * (1.0f / 96.0f);
  }
  __syncthreads();

  const int tile = tid >> 3, rt = tid & 7;    // 64 tiles x 8 ref-threads
  const float dt = sdens[tile];
  float best = -1e30f; int bi = 0;
#pragma unroll
  for (int qq = 0; qq < 12; ++qq) {
    const int r = rt * 12 + qq;
    if (r < 95) {
      const float s = sb2[tile * 97 + r] * (1.0f / 96.0f)
                    - 3.0f * fabsf(dt - densR[r]);
      if (s > best) { best = s; bi = r; }     // ascending r, strict >
    }
  }
#pragma unroll
  for (int m = 4; m >= 1; m >>= 1) {          // xor within the 8-lane tile group
    const float ob = __shfl_xor(best, m, 64);
    const int oi = __shfl_xor(bi, m, 64);
    if (ob > best || (ob == best && oi < bi)) { best = ob; bi = oi; }
  }
  if (rt == 0)
    out[(b2 >> 1) * 128 + (b2 & 1) * 64 + tile] = bi;
}

// ---- async global->LDS staging (FALLBACK kernel only) ----
__device__ __forceinline__ void stage_px(const float* __restrict__ src,
                                         float* dst, int lane) {
  const uintptr_t gs = (uintptr_t)src;
  const uintptr_t ls = (uintptr_t)dst;
#define G_(off) ((const __attribute__((address_space(1))) void*)(gs + (off)))
#define L_(off) ((__attribute__((address_space(3))) void*)(uint32_t)(ls + (off)))
  __builtin_amdgcn_global_load_lds(G_(0    + lane * 16), L_(0),    16, 0, 0);
  __builtin_amdgcn_global_load_lds(G_(1024 + lane * 16), L_(1024), 16, 0, 0);
  __builtin_amdgcn_global_load_lds(G_(2048 + lane * 16), L_(2048), 16, 0, 0);
  __builtin_amdgcn_global_load_lds(G_(3072 + lane * 16), L_(3072), 16, 0, 0);
  __builtin_amdgcn_global_load_lds(G_(4096 + lane * 4),  L_(4096), 4, 0, 0);
  __builtin_amdgcn_global_load_lds(G_(4352 + lane * 4),  L_(4352), 4, 0, 0);
#undef G_
#undef L_
}

// ---------------- Fallback: proven R7 single-kernel path (50 us) ----------------
// NOTE: fallback expects refdata permuted rows (rp = r/6 + 16*(r%6)); with the
// new identity layout its lane rthr reads rows rthr+16j == logical refs via
// rthr*... — to keep the fallback CORRECT with identity layout, its ref index
// mapping is adjusted: row (rthr + 16*j) now IS logical ref rthr+16j, and the
// argmax below maps r = rthr + 16*q accordingly (bijective coverage of 0..95).
__global__ __launch_bounds__(512, 2)
void ssim_full_kernel(
    const float* __restrict__ img, const float* __restrict__ refdata,
    const float* __restrict__ densR, int* __restrict__ out, KF kf) {
  __shared__ float smem[29184];
  __shared__ float densT[32];
  float* padT = smem;
  float* statT = smem + 4608;

  const int tid = threadIdx.x;
  const int w = tid >> 6;
  const int lane = tid & 63;
  const int tthr = lane >> 4;
  const int rthr = lane & 15;
  const int tl0 = tthr * 8;
  const int blk = blockIdx.x;
  const int row0 = blk >> 2;
  const int c0 = (blk & 3) * 32;
  const int hwBase = w * 12;
  float* rbuf = smem + 10752 + w * 2304;

  stage_px(refdata + (size_t)hwBase * 1152, rbuf, lane);

  for (int idx = tid; idx < 4608; idx += 512) {
    const int c = idx >> 5, tl = idx & 31;
    const int ph = c >> 3, pw = c & 7;
    const int h = refl(ph - 1, 16), ww = refl(pw - 1, 6);
    padT[idx] = img[(row0 * 16 + h) * 768 + (c0 + tl) * 6 + ww];
  }
  __syncthreads();

  if (tid < 32) {
    float s = 0.f;
    for (int h = 0; h < 16; ++h)
      for (int ww = 0; ww < 6; ++ww)
        s += padT[((h + 1) * 8 + (ww + 1)) * 32 + tid];
    densT[tid] = s * (1.0f / 96.0f);
  }
  for (int idx = tid; idx < 3072; idx += 512) {
    const int hw = idx >> 5, tl = idx & 31;
    const int h = hw / 6, ww = hw % 6;
    float mu = 0.f, ex2 = 0.f;
#pragma unroll
    for (int i = 0; i < 3; ++i)
#pragma unroll
      for (int j = 0; j < 3; ++j) {
        const float p = padT[((h + i) * 8 + (ww + j)) * 32 + tl];
        const float kv = kf.k[i * 3 + j];
        mu += kv * p;
        ex2 += kv * p * p;
      }
    statT[idx] = mu;
    statT[3072 + idx] = ex2 - mu * mu;
  }
  __syncthreads();

  float score[8][6];
#pragma unroll
  for (int i = 0; i < 8; ++i)
#pragma unroll
    for (int j = 0; j < 6; ++j) score[i][j] = 0.f;

  int w6 = 0;
  int pb = (2 * w) * 8 * 32 + tl0;
  int sbase = hwBase * 32 + tl0;
  const float* refsrc = refdata + (size_t)(hwBase + 1) * 1152;

#pragma unroll 1
  for (int it = 0; it < 12; ++it) {
    const float* buf = rbuf + (it & 1) * 1152;
    if (it < 11) {
      stage_px(refsrc, rbuf + ((it + 1) & 1) * 1152, lane);
      asm volatile("s_waitcnt vmcnt(6)" ::: "memory");
    } else {
      asm volatile("s_waitcnt vmcnt(0)" ::: "memory");
    }
    refsrc += 1152;

    float tp[9][8];
#pragma unroll
    for (int ik = 0; ik < 3; ++ik)
#pragma unroll
      for (int jk = 0; jk < 3; ++jk) {
        const int k = ik * 3 + jk;
        const float4 a = *(const float4*)&padT[pb + (ik * 8 + jk) * 32];
        const float4 b = *(const float4*)&padT[pb + (ik * 8 + jk) * 32 + 4];
        tp[k][0] = a.x; tp[k][1] = a.y; tp[k][2] = a.z; tp[k][3] = a.w;
        tp[k][4] = b.x; tp[k][5] = b.y; tp[k][6] = b.z; tp[k][7] = b.w;
      }
    float mu[8], sg[8], mt2[8];
    {
      float4 v;
      v = *(const float4*)&statT[sbase];            mu[0]=v.x; mu[1]=v.y; mu[2]=v.z; mu[3]=v.w;
      v = *(const float4*)&statT[sbase + 4];        mu[4]=v.x; mu[5]=v.y; mu[6]=v.z; mu[7]=v.w;
      v = *(const float4*)&statT[3072 + sbase];     sg[0]=v.x; sg[1]=v.y; sg[2]=v.z; sg[3]=v.w;
      v = *(const float4*)&statT[3072 + sbase + 4]; sg[4]=v.x; sg[5]=v.y; sg[6]=v.z; sg[7]=v.w;
#pragma unroll
      for (int i = 0; i < 8; ++i) mt2[i] = mu[i] * mu[i];
    }
#pragma unroll
    for (int j = 0; j < 6; ++j) {
      const int rb = (rthr + 16 * j) * 12;
      const float4 wa = *(const float4*)&buf[rb];
      const float4 wb = *(const float4*)&buf[rb + 4];
      const float4 wc = *(const float4*)&buf[rb + 8];
#pragma unroll
      for (int i = 0; i < 8; ++i) {
        float ev = fmaf(tp[0][i], wa.x, kC2);
        ev = fmaf(tp[1][i], wa.y, ev);
        ev = fmaf(tp[2][i], wa.z, ev);
        ev = fmaf(tp[3][i], wa.w, ev);
        ev = fmaf(tp[4][i], wb.x, ev);
        ev = fmaf(tp[5][i], wb.y, ev);
        ev = fmaf(tp[6][i], wb.z, ev);
        ev = fmaf(tp[7][i], wb.w, ev);
        ev = fmaf(tp[8][i], wc.x, ev);
        const float am = mu[i] * wc.y;
        const float n1 = am + kC1;
        const float n2 = ev - am;
        const float d1 = mt2[i] + wc.z;
        const float d2 = sg[i] + wc.w;
        const float r0v = __builtin_amdgcn_rcpf(d1 * d2);
        score[i][j] = fmaf(n1 * n2, r0v, score[i][j]);
      }
    }
    pb += (w6 == 5) ? 96 : 32;
    w6 = (w6 == 5) ? 0 : w6 + 1;
    sbase += 32;
  }

  __syncthreads();
  float* sb = smem;
#pragma unroll
  for (int i = 0; i < 8; ++i)
#pragma unroll
    for (int j = 0; j < 6; ++j)
      sb[w * 3104 + (tl0 + i) * 97 + (rthr + 16 * j)] = score[i][j];  // logical ref id
  __syncthreads();

  {
    const int tile = tid >> 4, rt = tid & 15;
    const float dt = densT[tile];
    float best = -1e30f; int bi = 0;
#pragma unroll
    for (int qq = 0; qq < 6; ++qq) {
      const int r = rt * 6 + qq;
      if (r < 95) {
        float s = 0.f;
#pragma unroll
        for (int g = 0; g < 8; ++g) s += sb[g * 3104 + tile * 97 + r];
        s = s * (1.0f / 96.0f) - 3.0f * fabsf(dt - densR[r]);
        if (s > best) { best = s; bi = r; }
      }
    }
#pragma unroll
    for (int m = 8; m >= 1; m >>= 1) {
      const float ob = __shfl_xor(best, m, 64);
      const int oi = __shfl_xor(bi, m, 64);
      if (ob > best || (ob == best && oi < bi)) { best = ob; bi = oi; }
    }
    if (rt == 0) out[row0 * 128 + c0 + tile] = bi;
  }
}

// ---------------- Host launch ----------------
extern "C" void kernel_launch(void* const* d_in, const int* in_sizes, int n_in,
                              void* d_out, int out_size, void* d_ws, size_t ws_size,
                              hipStream_t stream) {
  (void)in_sizes; (void)n_in; (void)out_size;
  const float* img = (const float*)d_in[0];
  const float* chars = (const float*)d_in[1];
  int* out = (int*)d_out;
  float* refdata = (float*)d_ws;                  // 110592 floats
  float* densR = refdata + 110592;                // +96
  float* part = refdata + 110688;                 // 4*128*6144 = 3145728 floats
  float* densP = part + 3145728;                  // 4*8192 floats
  const size_t need_bytes = (size_t)(110688 + 3145728 + 32768) * 4;

  KF kf;
  {
    float gg[3], s = 0.f;
    for (int i = 0; i < 3; ++i) {
      const float c = (float)i - 1.0f;
      gg[i] = expf(-(c * c) / (2.0f * 1.5f * 1.5f));
      s += gg[i];
    }
    float gn[3];
    for (int i = 0; i < 3; ++i) gn[i] = gg[i] / s;
    float k2[9]; float ks = 0.f;
    for (int i = 0; i < 3; ++i)
      for (int j = 0; j < 3; ++j) { k2[i * 3 + j] = gn[i] * gn[j]; ks += k2[i * 3 + j]; }
    for (int k = 0; k < 9; ++k) kf.k[k] = k2[k] / ks;
  }

  hipLaunchKernelGGL(refprep_kernel, dim3(96), dim3(128), 0, stream,
                     chars, refdata, densR, kf);
  if (ws_size >= need_bytes) {
    hipLaunchKernelGGL(ssim_reg_kernel, dim3(512), dim3(512), 0, stream,
                       img, refdata, part, densP, kf);
    hipLaunchKernelGGL(combine4_kernel, dim3(128), dim3(512), 0, stream,
                       part, densP, densR, out);
  } else {
    hipLaunchKernelGGL(ssim_full_kernel, dim3(256), dim3(512), 0, stream,
                       img, refdata, densR, out, kf);
  }
}

// Round 14
// 79.496 us; speedup vs baseline: 1.5360x; 1.5360x over previous
//
#include <hip/hip_runtime.h>
#include <math.h>

// SSIM char-matcher: img (1,1,1024,768) f32, chars (95,1,16,6) f32 -> argmax idx [64][128] int32
// H=16, W=6, WIN=3, tiles T=8192 (64 rows x 128 cols), refs R=95 (pad to 96)
//
// R14 "RegGEMM + scalar refs": lane = tile, wave owns 12 refs. Taps + stats
// are per-lane registers (11 ds_read_b32/px, reused across 12 refs). Ref rows
// are WAVE-UNIFORM -> pointer hoisted via readfirstlane so the compiler's
// uniformity analysis emits s_load (scalar cache, SGPR operands in the FMAs).
// R13's broadcast VECTOR loads serialized on L2 latency (~970 cyc/j, 116us);
// the scalar pipe removes that chain. Per wave-px: VALU ~504 cyc vs LDS ~64
// -> VALU-dominant 8:1.

static constexpr float kC1 = 1.0e-4f;   // 0.01^2
static constexpr float kC2 = 9.0e-4f;   // 0.03^2

struct KF { float k[9]; };

__device__ __forceinline__ int refl(int x, int n) {
  if (x < 0) return -x;
  if (x >= n) return 2 * n - 2 - x;
  return x;
}

// ---------------- Kernel 1: per-ref precompute ----------------
// refdata: [hw 96][r 96][12 floats] (row = 48 B, 16B-aligned).
// Row: f0..8 = 2*k[k]*Rp[k] (DOUBLED), f9 = 2*mu_r (DOUBLED),
// f10 = mu_r^2 + C1, f11 = sig_r + C2.  r=95 is padding (never argmax'd).
__global__ __launch_bounds__(128) void refprep_kernel(
    const float* __restrict__ chars, float* __restrict__ refdata,
    float* __restrict__ densR, KF kf) {
  const int hw = blockIdx.x;   // 0..95
  const int r = threadIdx.x;   // 0..127
  if (r >= 96) return;
  float* row = refdata + ((size_t)hw * 96 + r) * 12;
  const int h = hw / 6, w = hw % 6;
  if (r < 95) {
    const float* cb = chars + r * 96;
    float mu = 0.f, ex2 = 0.f;
    float wrv[9];
#pragma unroll
    for (int i = 0; i < 3; ++i) {
      const int hh = refl(h + i - 1, 16);
#pragma unroll
      for (int j = 0; j < 3; ++j) {
        const int ww = refl(w + j - 1, 6);
        const float p = cb[hh * 6 + ww];
        const float kv = kf.k[i * 3 + j];
        wrv[i * 3 + j] = 2.0f * kv * p;
        mu += kv * p;
        ex2 += kv * p * p;
      }
    }
    const float sig = ex2 - mu * mu;
#pragma unroll
    for (int k = 0; k < 9; ++k) row[k] = wrv[k];
    row[9]  = 2.0f * mu;
    row[10] = mu * mu + kC1;
    row[11] = sig + kC2;
  } else {
#pragma unroll
    for (int k = 0; k < 9; ++k) row[k] = 0.f;
    row[9]  = 0.f;
    row[10] = kC1;
    row[11] = kC2;
  }
  if (hw == 0) {
    if (r < 95) {
      float s = 0.f;
      for (int i = 0; i < 96; ++i) s += chars[r * 96 + i];
      densR[r] = s * (1.0f / 96.0f);
    } else {
      densR[r] = 0.f;
    }
  }
}

// ---------------- Kernel 2a: main SSIM (px-quarter, reg taps, scalar refs) ----------------
// Grid 512 = (64 rows) x (2 tile-halves of 64) x (4 px-quarters of 24).
// part[q 4][b2 128][r 96][t 64]; densP[q 4][8192].
__global__ __launch_bounds__(512, 2)
void ssim_reg_kernel(
    const float* __restrict__ img, const float* __restrict__ refdata,
    float* __restrict__ part, float* __restrict__ densP, KF kf) {
  __shared__ float padT[3072];    // [6 prow][8 pcol][64 tile]
  __shared__ float statT[3072];   // [2][24 px][64 tile]

  const int tid = threadIdx.x;
  const int lane = tid & 63;      // tile 0..63
  const int w = tid >> 6;         // wave 0..7 -> refs [12w, 12w+12)
  const int blk = blockIdx.x;
  const int q = blk & 3;          // px-quarter: pixel rows [4q, 4q+4)
  const int b2 = blk >> 2;        // 0..127
  const int row0 = b2 >> 1;       // tile-row 0..63
  const int ch = b2 & 1;          // tile-half: tiles [64ch, 64ch+64)

  // Phase A: reflect-padded rows 4q-1..4q+4 of this tile-row, transposed.
  for (int idx = tid; idx < 3072; idx += 512) {
    const int c = idx >> 6, tl = idx & 63;
    const int pr = c >> 3, pc = c & 7;
    const int h = refl(q * 4 + pr - 1, 16), ww = refl(pc - 1, 6);
    padT[idx] = img[(row0 * 16 + h) * 768 + ch * 384 + tl * 6 + ww];
  }
  __syncthreads();

  // Quarter tile-density partial (4 interior rows x 6 cols), raw sum.
  if (tid < 64) {
    float s = 0.f;
    for (int pr = 1; pr <= 4; ++pr)
      for (int pc = 1; pc <= 6; ++pc)
        s += padT[(pr * 8 + pc) * 64 + tid];
    densP[q * 8192 + row0 * 128 + ch * 64 + tid] = s;
  }
  // Phase B: per-(local px, tile) stats: mu, sig.
  for (int idx = tid; idx < 1536; idx += 512) {
    const int hwl = idx >> 6, tl = idx & 63;
    const int hl = hwl / 6, wl = hwl - hl * 6;
    float mu = 0.f, ex2 = 0.f;
#pragma unroll
    for (int i = 0; i < 3; ++i)
#pragma unroll
      for (int j = 0; j < 3; ++j) {
        const float p = padT[((hl + i) * 8 + (wl + j)) * 64 + tl];
        const float kv = kf.k[i * 3 + j];
        mu += kv * p;
        ex2 += kv * p * p;
      }
    statT[idx] = mu;
    statT[1536 + idx] = ex2 - mu * mu;
  }
  __syncthreads();

  float score[12];
#pragma unroll
  for (int j = 0; j < 12; ++j) score[j] = 0.f;

  int tapoff = lane;              // float index of window origin (r6=0,c6=0)
  int statoff = lane;
  int c6 = 0;
  // readfirstlane: make the wave's ref-block pointer PROVABLY uniform so the
  // compiler emits s_load (SGPR data, scalar cache) instead of per-lane
  // vector loads. Each FMA then reads the ref weight as its 1 SGPR operand.
  const int wu = __builtin_amdgcn_readfirstlane(w);
  const float* refpx = refdata + (size_t)(q * 24) * 1152 + wu * 144;

#pragma unroll 1
  for (int p = 0; p < 24; ++p) {
    // 9 taps + stats for this lane's tile at this px (LDS b32, reused x12 refs)
    const float t0 = padT[tapoff];
    const float t1 = padT[tapoff + 64];
    const float t2 = padT[tapoff + 128];
    const float t3 = padT[tapoff + 512];
    const float t4 = padT[tapoff + 576];
    const float t5 = padT[tapoff + 640];
    const float t6 = padT[tapoff + 1024];
    const float t7 = padT[tapoff + 1088];
    const float t8 = padT[tapoff + 1152];
    const float mu = statT[statoff];
    const float sg = statT[1536 + statoff];
    const float mt2 = mu * mu;

    // Two 6-ref halves: <=72 live scalar floats + overhead fits SGPR budget.
#pragma unroll 1
    for (int jh = 0; jh < 2; ++jh) {
#pragma unroll
      for (int j6 = 0; j6 < 6; ++j6) {
        const int j = jh * 6 + j6;
        const float* rw = refpx + j * 12;   // uniform -> scalar loads
        const float w0 = rw[0], w1 = rw[1], w2 = rw[2], w3 = rw[3];
        const float w4 = rw[4], w5 = rw[5], w6 = rw[6], w7 = rw[7];
        const float w8 = rw[8], w9 = rw[9], w10 = rw[10], w11 = rw[11];
        float ev = fmaf(t0, w0, kC2);
        ev = fmaf(t1, w1, ev);
        ev = fmaf(t2, w2, ev);
        ev = fmaf(t3, w3, ev);
        ev = fmaf(t4, w4, ev);
        ev = fmaf(t5, w5, ev);
        ev = fmaf(t6, w6, ev);
        ev = fmaf(t7, w7, ev);
        ev = fmaf(t8, w8, ev);
        // w9 = 2*mu_r, w10 = mu_r^2+C1, w11 = sig_r+C2
        const float am = mu * w9;                // 2*mt*mr
        const float n1 = am + kC1;
        const float n2 = ev - am;                // 2*sig_tr + C2
        const float d1 = mt2 + w10;              // mt^2+mr^2+C1
        const float d2 = sg + w11;
        const float r0v = __builtin_amdgcn_rcpf(d1 * d2);  // ~1-ulp (absmax 0 since R8)
        score[j] = fmaf(n1 * n2, r0v, score[j]);
      }
    }

    tapoff += (c6 == 5) ? 192 : 64;   // col step; row wrap: +3 window cols
    c6 = (c6 == 5) ? 0 : c6 + 1;
    statoff += 64;
    refpx += 1152;
  }

  // Write per-(ref, tile) partials: coalesced 64-lane rows.
  float* dst = part + ((size_t)q * 128 + b2) * 6144 + (w * 12) * 64 + lane;
#pragma unroll
  for (int j = 0; j < 12; ++j) dst[j * 64] = score[j];
}

// ---------------- Kernel 2b: combine quarters + density + argmax ----------------
__global__ __launch_bounds__(512) void combine4_kernel(
    const float* __restrict__ part, const float* __restrict__ densP,
    const float* __restrict__ densR, int* __restrict__ out) {
  __shared__ float sb2[64 * 97];
  __shared__ float sdens[64];
  const int tid = threadIdx.x;
  const int b2 = blockIdx.x;          // 0..127

  for (int idx = tid; idx < 6144; idx += 512) {
    const int r = idx >> 6, t = idx & 63;
    const float s = part[(size_t)(0 * 128 + b2) * 6144 + idx]
                  + part[(size_t)(1 * 128 + b2) * 6144 + idx]
                  + part[(size_t)(2 * 128 + b2) * 6144 + idx]
                  + part[(size_t)(3 * 128 + b2) * 6144 + idx];
    sb2[t * 97 + r] = s;
  }
  if (tid < 64) {
    const int gt = (b2 >> 1) * 128 + (b2 & 1) * 64 + tid;
    sdens[tid] = (densP[gt] + densP[8192 + gt] + densP[16384 + gt]
                  + densP[24576 + gt]) * (1.0f / 96.0f);
  }
  __syncthreads();

  const int tile = tid >> 3, rt = tid & 7;    // 64 tiles x 8 ref-threads
  const float dt = sdens[tile];
  float best = -1e30f; int bi = 0;
#pragma unroll
  for (int qq = 0; qq < 12; ++qq) {
    const int r = rt * 12 + qq;
    if (r < 95) {
      const float s = sb2[tile * 97 + r] * (1.0f / 96.0f)
                    - 3.0f * fabsf(dt - densR[r]);
      if (s > best) { best = s; bi = r; }     // ascending r, strict >
    }
  }
#pragma unroll
  for (int m = 4; m >= 1; m >>= 1) {          // xor within the 8-lane tile group
    const float ob = __shfl_xor(best, m, 64);
    const int oi = __shfl_xor(bi, m, 64);
    if (ob > best || (ob == best && oi < bi)) { best = ob; bi = oi; }
  }
  if (rt == 0)
    out[(b2 >> 1) * 128 + (b2 & 1) * 64 + tile] = bi;
}

// ---- async global->LDS staging (FALLBACK kernel only) ----
__device__ __forceinline__ void stage_px(const float* __restrict__ src,
                                         float* dst, int lane) {
  const uintptr_t gs = (uintptr_t)src;
  const uintptr_t ls = (uintptr_t)dst;
#define G_(off) ((const __attribute__((address_space(1))) void*)(gs + (off)))
#define L_(off) ((__attribute__((address_space(3))) void*)(uint32_t)(ls + (off)))
  __builtin_amdgcn_global_load_lds(G_(0    + lane * 16), L_(0),    16, 0, 0);
  __builtin_amdgcn_global_load_lds(G_(1024 + lane * 16), L_(1024), 16, 0, 0);
  __builtin_amdgcn_global_load_lds(G_(2048 + lane * 16), L_(2048), 16, 0, 0);
  __builtin_amdgcn_global_load_lds(G_(3072 + lane * 16), L_(3072), 16, 0, 0);
  __builtin_amdgcn_global_load_lds(G_(4096 + lane * 4),  L_(4096), 4, 0, 0);
  __builtin_amdgcn_global_load_lds(G_(4352 + lane * 4),  L_(4352), 4, 0, 0);
#undef G_
#undef L_
}

// ---------------- Fallback: proven R7-structure path (identity ref layout) ----------------
__global__ __launch_bounds__(512, 2)
void ssim_full_kernel(
    const float* __restrict__ img, const float* __restrict__ refdata,
    const float* __restrict__ densR, int* __restrict__ out, KF kf) {
  __shared__ float smem[29184];
  __shared__ float densT[32];
  float* padT = smem;
  float* statT = smem + 4608;

  const int tid = threadIdx.x;
  const int w = tid >> 6;
  const int lane = tid & 63;
  const int tthr = lane >> 4;
  const int rthr = lane & 15;
  const int tl0 = tthr * 8;
  const int blk = blockIdx.x;
  const int row0 = blk >> 2;
  const int c0 = (blk & 3) * 32;
  const int hwBase = w * 12;
  float* rbuf = smem + 10752 + w * 2304;

  stage_px(refdata + (size_t)hwBase * 1152, rbuf, lane);

  for (int idx = tid; idx < 4608; idx += 512) {
    const int c = idx >> 5, tl = idx & 31;
    const int ph = c >> 3, pw = c & 7;
    const int h = refl(ph - 1, 16), ww = refl(pw - 1, 6);
    padT[idx] = img[(row0 * 16 + h) * 768 + (c0 + tl) * 6 + ww];
  }
  __syncthreads();

  if (tid < 32) {
    float s = 0.f;
    for (int h = 0; h < 16; ++h)
      for (int ww = 0; ww < 6; ++ww)
        s += padT[((h + 1) * 8 + (ww + 1)) * 32 + tid];
    densT[tid] = s * (1.0f / 96.0f);
  }
  for (int idx = tid; idx < 3072; idx += 512) {
    const int hw = idx >> 5, tl = idx & 31;
    const int h = hw / 6, ww = hw % 6;
    float mu = 0.f, ex2 = 0.f;
#pragma unroll
    for (int i = 0; i < 3; ++i)
#pragma unroll
      for (int j = 0; j < 3; ++j) {
        const float p = padT[((h + i) * 8 + (ww + j)) * 32 + tl];
        const float kv = kf.k[i * 3 + j];
        mu += kv * p;
        ex2 += kv * p * p;
      }
    statT[idx] = mu;
    statT[3072 + idx] = ex2 - mu * mu;
  }
  __syncthreads();

  float score[8][6];
#pragma unroll
  for (int i = 0; i < 8; ++i)
#pragma unroll
    for (int j = 0; j < 6; ++j) score[i][j] = 0.f;

  int w6 = 0;
  int pb = (2 * w) * 8 * 32 + tl0;
  int sbase = hwBase * 32 + tl0;
  const float* refsrc = refdata + (size_t)(hwBase + 1) * 1152;

#pragma unroll 1
  for (int it = 0; it < 12; ++it) {
    const float* buf = rbuf + (it & 1) * 1152;
    if (it < 11) {
      stage_px(refsrc, rbuf + ((it + 1) & 1) * 1152, lane);
      asm volatile("s_waitcnt vmcnt(6)" ::: "memory");
    } else {
      asm volatile("s_waitcnt vmcnt(0)" ::: "memory");
    }
    refsrc += 1152;

    float tp[9][8];
#pragma unroll
    for (int ik = 0; ik < 3; ++ik)
#pragma unroll
      for (int jk = 0; jk < 3; ++jk) {
        const int k = ik * 3 + jk;
        const float4 a = *(const float4*)&padT[pb + (ik * 8 + jk) * 32];
        const float4 b = *(const float4*)&padT[pb + (ik * 8 + jk) * 32 + 4];
        tp[k][0] = a.x; tp[k][1] = a.y; tp[k][2] = a.z; tp[k][3] = a.w;
        tp[k][4] = b.x; tp[k][5] = b.y; tp[k][6] = b.z; tp[k][7] = b.w;
      }
    float mu[8], sg[8], mt2[8];
    {
      float4 v;
      v = *(const float4*)&statT[sbase];            mu[0]=v.x; mu[1]=v.y; mu[2]=v.z; mu[3]=v.w;
      v = *(const float4*)&statT[sbase + 4];        mu[4]=v.x; mu[5]=v.y; mu[6]=v.z; mu[7]=v.w;
      v = *(const float4*)&statT[3072 + sbase];     sg[0]=v.x; sg[1]=v.y; sg[2]=v.z; sg[3]=v.w;
      v = *(const float4*)&statT[3072 + sbase + 4]; sg[4]=v.x; sg[5]=v.y; sg[6]=v.z; sg[7]=v.w;
#pragma unroll
      for (int i = 0; i < 8; ++i) mt2[i] = mu[i] * mu[i];
    }
#pragma unroll
    for (int j = 0; j < 6; ++j) {
      const int rb = (rthr + 16 * j) * 12;
      const float4 wa = *(const float4*)&buf[rb];
      const float4 wb = *(const float4*)&buf[rb + 4];
      const float4 wc = *(const float4*)&buf[rb + 8];
#pragma unroll
      for (int i = 0; i < 8; ++i) {
        float ev = fmaf(tp[0][i], wa.x, kC2);
        ev = fmaf(tp[1][i], wa.y, ev);
        ev = fmaf(tp[2][i], wa.z, ev);
        ev = fmaf(tp[3][i], wa.w, ev);
        ev = fmaf(tp[4][i], wb.x, ev);
        ev = fmaf(tp[5][i], wb.y, ev);
        ev = fmaf(tp[6][i], wb.z, ev);
        ev = fmaf(tp[7][i], wb.w, ev);
        ev = fmaf(tp[8][i], wc.x, ev);
        const float am = mu[i] * wc.y;
        const float n1 = am + kC1;
        const float n2 = ev - am;
        const float d1 = mt2[i] + wc.z;
        const float d2 = sg[i] + wc.w;
        const float r0v = __builtin_amdgcn_rcpf(d1 * d2);
        score[i][j] = fmaf(n1 * n2, r0v, score[i][j]);
      }
    }
    pb += (w6 == 5) ? 96 : 32;
    w6 = (w6 == 5) ? 0 : w6 + 1;
    sbase += 32;
  }

  __syncthreads();
  float* sb = smem;
#pragma unroll
  for (int i = 0; i < 8; ++i)
#pragma unroll
    for (int j = 0; j < 6; ++j)
      sb[w * 3104 + (tl0 + i) * 97 + (rthr + 16 * j)] = score[i][j];  // logical ref id
  __syncthreads();

  {
    const int tile = tid >> 4, rt = tid & 15;
    const float dt = densT[tile];
    float best = -1e30f; int bi = 0;
#pragma unroll
    for (int qq = 0; qq < 6; ++qq) {
      const int r = rt * 6 + qq;
      if (r < 95) {
        float s = 0.f;
#pragma unroll
        for (int g = 0; g < 8; ++g) s += sb[g * 3104 + tile * 97 + r];
        s = s * (1.0f / 96.0f) - 3.0f * fabsf(dt - densR[r]);
        if (s > best) { best = s; bi = r; }
      }
    }
#pragma unroll
    for (int m = 8; m >= 1; m >>= 1) {
      const float ob = __shfl_xor(best, m, 64);
      const int oi = __shfl_xor(bi, m, 64);
      if (ob > best || (ob == best && oi < bi)) { best = ob; bi = oi; }
    }
    if (rt == 0) out[row0 * 128 + c0 + tile] = bi;
  }
}

// ---------------- Host launch ----------------
extern "C" void kernel_launch(void* const* d_in, const int* in_sizes, int n_in,
                              void* d_out, int out_size, void* d_ws, size_t ws_size,
                              hipStream_t stream) {
  (void)in_sizes; (void)n_in; (void)out_size;
  const float* img = (const float*)d_in[0];
  const float* chars = (const float*)d_in[1];
  int* out = (int*)d_out;
  float* refdata = (float*)d_ws;                  // 110592 floats
  float* densR = refdata + 110592;                // +96
  float* part = refdata + 110688;                 // 4*128*6144 = 3145728 floats
  float* densP = part + 3145728;                  // 4*8192 floats
  const size_t need_bytes = (size_t)(110688 + 3145728 + 32768) * 4;

  KF kf;
  {
    float gg[3], s = 0.f;
    for (int i = 0; i < 3; ++i) {
      const float c = (float)i - 1.0f;
      gg[i] = expf(-(c * c) / (2.0f * 1.5f * 1.5f));
      s += gg[i];
    }
    float gn[3];
    for (int i = 0; i < 3; ++i) gn[i] = gg[i] / s;
    float k2[9]; float ks = 0.f;
    for (int i = 0; i < 3; ++i)
      for (int j = 0; j < 3; ++j) { k2[i * 3 + j] = gn[i] * gn[j]; ks += k2[i * 3 + j]; }
    for (int k = 0; k < 9; ++k) kf.k[k] = k2[k] / ks;
  }

  hipLaunchKernelGGL(refprep_kernel, dim3(96), dim3(128), 0, stream,
                     chars, refdata, densR, kf);
  if (ws_size >= need_bytes) {
    hipLaunchKernelGGL(ssim_reg_kernel, dim3(512), dim3(512), 0, stream,
                       img, refdata, part, densP, kf);
    hipLaunchKernelGGL(combine4_kernel, dim3(128), dim3(512), 0, stream,
                       part, densP, densR, out);
  } else {
    hipLaunchKernelGGL(ssim_full_kernel, dim3(256), dim3(512), 0, stream,
                       img, refdata, densR, out, kf);
  }
}